// Round 8
// baseline (2222.859 us; speedup 1.0000x reference)
//
#include <hip/hip_runtime.h>
#include <math.h>

#define NN   100000
#define EE   1600000
#define ET   (EE + NN)          // edges + self-loops = 1,700,000
#define HID  64
#define MLPH 128
#define ODIM 74
#define SLOPE 0.2f

#define NB   196                // coarse buckets of 512 nodes (dst >> 9)
#define GA   800                // pass-A blocks
#define EPB  (EE / GA)          // 2000 edges per pass-A block

__device__ __forceinline__ float f4get(const float4& v, int i) {
    return i == 0 ? v.x : i == 1 ? v.y : i == 2 ? v.z : v.w;  // unrolled -> constant
}

// ================= CSR build: bucketed counting sort, no global atomics =================

// Pass A1: per-block LDS histogram over 196 coarse buckets
__global__ void k_partA_hist(const int* __restrict__ edst, int* __restrict__ M) {
    __shared__ int hist[NB];
    int t = threadIdx.x;
    if (t < NB) hist[t] = 0;
    __syncthreads();
    int base = blockIdx.x * EPB;
    for (int i = t; i < EPB; i += 256)
        atomicAdd(&hist[edst[base + i] >> 9], 1);
    __syncthreads();
    if (t < NB) M[blockIdx.x * NB + t] = hist[t];
}

// scan each bucket-column over the GA blocks: colExcl[b,k] = sum_{b'<b} M[b',k]; colsum[k]=total
__global__ void k_scan_col(const int* __restrict__ M, int* __restrict__ colExcl,
                           int* __restrict__ colsum) {
    __shared__ int sd[256];
    __shared__ int carry;
    int k = blockIdx.x, t = threadIdx.x;
    if (t == 0) carry = 0;
    __syncthreads();
    for (int c = 0; c < GA; c += 256) {
        int v = (c + t < GA) ? M[(c + t) * NB + k] : 0;
        sd[t] = v;
        __syncthreads();
        for (int o = 1; o < 256; o <<= 1) {
            int u = (t >= o) ? sd[t - o] : 0;
            __syncthreads();
            sd[t] += u;
            __syncthreads();
        }
        if (c + t < GA) colExcl[(c + t) * NB + k] = carry + sd[t] - v;
        __syncthreads();
        if (t == 255) carry += sd[255];
        __syncthreads();
    }
    if (t == 0) colsum[k] = carry;
}

// exclusive scan of the 196 bucket totals
__global__ void k_scan_bkt(const int* __restrict__ colsum, int* __restrict__ bucketBase) {
    __shared__ int sd[256];
    int t = threadIdx.x;
    int v = (t < NB) ? colsum[t] : 0;
    sd[t] = v;
    __syncthreads();
    for (int o = 1; o < 256; o <<= 1) {
        int u = (t >= o) ? sd[t - o] : 0;
        __syncthreads();
        sd[t] += u;
        __syncthreads();
    }
    if (t < NB) bucketBase[t] = sd[t] - v;
    if (t == NB - 1) bucketBase[NB] = sd[t];
}

// Pass A2: scatter packed (dst,src) into bucket-partitioned tmp via LDS cursors
__global__ void k_partA_scat(const int* __restrict__ esrc, const int* __restrict__ edst,
                             const int* __restrict__ colExcl, const int* __restrict__ bucketBase,
                             unsigned long long* __restrict__ tmp) {
    __shared__ int cur[NB];
    int t = threadIdx.x;
    if (t < NB) cur[t] = bucketBase[t] + colExcl[blockIdx.x * NB + t];
    __syncthreads();
    int base = blockIdx.x * EPB;
    for (int i = t; i < EPB; i += 256) {
        int s = esrc[base + i], d = edst[base + i];
        int pos = atomicAdd(&cur[d >> 9], 1);
        tmp[pos] = ((unsigned long long)(unsigned)d << 32) | (unsigned)s;
    }
}

// Pass B: one block per bucket — LDS deg hist + LDS scan + LDS-cursor scatter into col;
// emits rowbeg/rowend with self-loop pre-placed at each row head.
__global__ __launch_bounds__(512) void k_partB(
        const unsigned long long* __restrict__ tmp, const int* __restrict__ bucketBase,
        int* __restrict__ rowbeg, int* __restrict__ rowend, int* __restrict__ col) {
    __shared__ int deg[512];
    __shared__ int rb[512];
    __shared__ int cur[512];
    int k = blockIdx.x, t = threadIdx.x;
    int lo = bucketBase[k], hi = bucketBase[k + 1];
    int nodeBase = k << 9;
    int nNodes = (NN - nodeBase < 512) ? (NN - nodeBase) : 512;

    deg[t] = 0;
    __syncthreads();
    for (int i = lo + t; i < hi; i += 512)
        atomicAdd(&deg[(int)(tmp[i] >> 32) - nodeBase], 1);
    __syncthreads();

    // exclusive scan over (deg + 1 self-loop) for the bucket's nodes
    int v = (t < nNodes) ? deg[t] + 1 : 0;
    rb[t] = v;
    __syncthreads();
    for (int o = 1; o < 512; o <<= 1) {
        int u = (t >= o) ? rb[t - o] : 0;
        __syncthreads();
        rb[t] += u;
        __syncthreads();
    }
    // global col segment for bucket k starts at bucketBase[k] + (#self-loops before) = nodeBase
    int myBeg = lo + nodeBase + rb[t] - v;
    if (t < nNodes) {
        int g = nodeBase + t;
        rowbeg[g] = myBeg;
        rowend[g] = myBeg + deg[t] + 1;
        col[myBeg] = g;              // self-loop first in row
        cur[t] = myBeg + 1;
    }
    __syncthreads();
    for (int i = lo + t; i < hi; i += 512) {
        unsigned long long e = tmp[i];
        int dLow = (int)(e >> 32) - nodeBase;
        int pos = atomicAdd(&cur[dLow], 1);
        col[pos] = (int)(e & 0xffffffffu);
    }
}

// ---------------- dense prologues ----------------

// h = x @ W1 (IN_DIM=3) + hs/hd wave reductions
__global__ void k_lin1(const float* __restrict__ x, const float* __restrict__ W,
                       const float* __restrict__ asrc, const float* __restrict__ adst,
                       float* __restrict__ h, float* __restrict__ hs, float* __restrict__ hd) {
    int node = blockIdx.x * 4 + (threadIdx.x >> 6);
    int f    = threadIdx.x & 63;
    float x0 = x[node*3+0], x1 = x[node*3+1], x2 = x[node*3+2];
    float v  = x0*W[f] + x1*W[64+f] + x2*W[128+f];
    h[node*64+f] = v;
    float ps = v*asrc[f], pd = v*adst[f];
    #pragma unroll
    for (int o = 32; o > 0; o >>= 1) { ps += __shfl_down(ps, o); pd += __shfl_down(pd, o); }
    if (f == 0) { hs[node] = ps; hd[node] = pd; }
}

// h = xin @ W (64x64): 32 nodes/block, 128 threads, 4x4 tile/thread, LDS-staged W
__global__ __launch_bounds__(128) void k_lin64(
        const float* __restrict__ xin, const float* __restrict__ W,
        const float* __restrict__ asrc, const float* __restrict__ adst,
        float* __restrict__ h, float* __restrict__ hs, float* __restrict__ hd) {
    __shared__ __align__(16) float xr[32][64];     // 8 KB (x rows, later reused for h rows)
    __shared__ __align__(16) float wl[64*64];      // 16 KB, [k][o] layout
    int t  = threadIdx.x;
    int nb = blockIdx.x * 32;
    for (int i = t; i < 32*64; i += 128) xr[i >> 6][i & 63] = xin[nb*64 + i];
    for (int i = t; i < 64*64;  i += 128) wl[i] = W[i];
    __syncthreads();

    int nq = t >> 4;    // 0..7 (4 nodes each)
    int hq = t & 15;    // 0..15 (4 outs each)
    float acc[4][4] = {};
    for (int k = 0; k < 64; k += 4) {
        float4 xv[4];
        #pragma unroll
        for (int ni = 0; ni < 4; ++ni) xv[ni] = *(const float4*)&xr[nq*4+ni][k];
        #pragma unroll
        for (int kk = 0; kk < 4; ++kk) {
            float4 wv = *(const float4*)&wl[(k+kk)*64 + hq*4];
            #pragma unroll
            for (int ni = 0; ni < 4; ++ni) {
                float xs = f4get(xv[ni], kk);
                acc[ni][0] += xs*wv.x; acc[ni][1] += xs*wv.y;
                acc[ni][2] += xs*wv.z; acc[ni][3] += xs*wv.w;
            }
        }
    }
    float4 res[4];
    #pragma unroll
    for (int ni = 0; ni < 4; ++ni) {
        res[ni] = make_float4(acc[ni][0], acc[ni][1], acc[ni][2], acc[ni][3]);
        *(float4*)&h[(size_t)(nb + nq*4 + ni)*64 + hq*4] = res[ni];
    }
    __syncthreads();                 // all xr reads done
    #pragma unroll
    for (int ni = 0; ni < 4; ++ni) *(float4*)&xr[nq*4+ni][hq*4] = res[ni];
    __syncthreads();

    // hs/hd: 2 waves x 16 nodes, lane = feature
    int wv_  = t >> 6;
    int lane = t & 63;
    for (int ni = 0; ni < 16; ++ni) {
        int node = wv_*16 + ni;
        float v  = xr[node][lane];
        float ps = v*asrc[lane], pd = v*adst[lane];
        #pragma unroll
        for (int o = 32; o > 0; o >>= 1) { ps += __shfl_down(ps, o); pd += __shfl_down(pd, o); }
        if (lane == 0) { hs[nb+node] = ps; hd[nb+node] = pd; }
    }
}

// ---------------- fused GAT aggregate: one wave per dst node ----------------
__global__ void k_gat(const int* __restrict__ rowbeg, const int* __restrict__ rowend,
                      const int* __restrict__ col,
                      const float* __restrict__ hs, const float* __restrict__ hd,
                      const float* __restrict__ h, const float* __restrict__ bias,
                      float* __restrict__ out) {
    __shared__ float se[4][128];
    __shared__ int   sc[4][128];
    int w    = threadIdx.x >> 6;
    int lane = threadIdx.x & 63;
    int n    = blockIdx.x * 4 + w;
    float* e_ = se[w];
    int*   c_ = sc[w];

    int base = rowbeg[n];
    int d    = rowend[n] - base;          // >=1 (self-loop)
    float hdn = hd[n];

    // phase A1: scores (+ stash col) + wave max
    float mymax = -INFINITY;
    for (int k = lane; k < d; k += 64) {
        int s = col[base + k];
        float scv = hs[s] + hdn;
        scv = (scv > 0.f) ? scv : SLOPE * scv;
        if (k < 128) { e_[k] = scv; c_[k] = s; }
        mymax = fmaxf(mymax, scv);
    }
    #pragma unroll
    for (int o = 32; o > 0; o >>= 1) mymax = fmaxf(mymax, __shfl_xor(mymax, o));

    // phase A2: exp + wave sum (own elements only)
    float mysum = 0.f;
    for (int k = lane; k < d; k += 64) {
        float scv;
        if (k < 128) scv = e_[k];
        else {
            int s = col[base + k];
            scv = hs[s] + hdn;
            scv = (scv > 0.f) ? scv : SLOPE * scv;
        }
        float p = expf(scv - mymax);
        if (k < 128) e_[k] = p;
        mysum += p;
    }
    #pragma unroll
    for (int o = 32; o > 0; o >>= 1) mysum += __shfl_xor(mysum, o);
    float inv = 1.f / mysum;

    __syncthreads();   // publish p/col for cross-lane reads

    // phase B: unroll x4, 4 independent h-row loads in flight
    int dl = (d < 128) ? d : 128;
    float accf = 0.f;
    int k = 0;
    for (; k + 4 <= dl; k += 4) {
        int s0 = c_[k], s1 = c_[k+1], s2 = c_[k+2], s3 = c_[k+3];
        float p0 = e_[k], p1 = e_[k+1], p2 = e_[k+2], p3 = e_[k+3];
        float h0 = h[(size_t)s0*64 + lane];
        float h1 = h[(size_t)s1*64 + lane];
        float h2 = h[(size_t)s2*64 + lane];
        float h3 = h[(size_t)s3*64 + lane];
        accf += p0*h0 + p1*h1 + p2*h2 + p3*h3;
    }
    for (; k < dl; ++k) accf += e_[k] * h[(size_t)c_[k]*64 + lane];
    for (; k < d; ++k) {                   // d>128 spill path (never hit at E[deg]=17)
        int s = col[base + k];
        float scv = hs[s] + hdn;
        scv = (scv > 0.f) ? scv : SLOPE * scv;
        accf += expf(scv - mymax) * h[(size_t)s*64 + lane];
    }
    out[n*64 + lane] = fmaxf(accf*inv + bias[lane], 0.f);
}

// ---------------- MLP head v4: float4 LDS reads (ds_read_b128), weights from global ----------------
__global__ __launch_bounds__(256) void k_mlp(
        const float* __restrict__ xin,
        const float* __restrict__ Wp1, const float* __restrict__ bp1,
        const float* __restrict__ Wp2, const float* __restrict__ bp2,
        float* __restrict__ out) {
    __shared__ __align__(16) float xr[32][64];     // 8 KB
    __shared__ __align__(16) float hid[32][132];   // 16.9 KB; row stride 132 = 33x16B (f4-aligned)
    int t  = threadIdx.x;
    int nb = blockIdx.x * 32;
    int nq = t >> 5;      // 0..7  (4 nodes each)
    int hq = t & 31;      // 0..31 (4 hidden units each in phase 1)

    for (int i = t; i < 32*64; i += 256) xr[i >> 6][i & 63] = xin[(size_t)nb*64 + i];
    __syncthreads();

    // phase 1: hid = relu(x @ Wp1 + bp1); x rows via ds_read_b128, weights from global (L1)
    {
        float4 bv = *(const float4*)&bp1[hq*4];
        float acc[4][4];
        #pragma unroll
        for (int ni = 0; ni < 4; ++ni) {
            acc[ni][0] = bv.x; acc[ni][1] = bv.y; acc[ni][2] = bv.z; acc[ni][3] = bv.w;
        }
        for (int k = 0; k < 64; k += 4) {
            float4 xv[4];
            #pragma unroll
            for (int ni = 0; ni < 4; ++ni) xv[ni] = *(const float4*)&xr[nq*4+ni][k];
            #pragma unroll
            for (int kk = 0; kk < 4; ++kk) {
                float4 wv = *(const float4*)&Wp1[(k+kk)*MLPH + hq*4];
                #pragma unroll
                for (int ni = 0; ni < 4; ++ni) {
                    float xs = f4get(xv[ni], kk);
                    acc[ni][0] += xs*wv.x; acc[ni][1] += xs*wv.y;
                    acc[ni][2] += xs*wv.z; acc[ni][3] += xs*wv.w;
                }
            }
        }
        #pragma unroll
        for (int ni = 0; ni < 4; ++ni)
            *(float4*)&hid[nq*4+ni][hq*4] = make_float4(
                fmaxf(acc[ni][0], 0.f), fmaxf(acc[ni][1], 0.f),
                fmaxf(acc[ni][2], 0.f), fmaxf(acc[ni][3], 0.f));
    }
    __syncthreads();

    // phase 2: out = hid @ Wp2 + bp2; hid rows via ds_read_b128;
    // thread = (nq: 4 nodes, oq: outs oq, oq+32, oq+64)
    {
        int oq = t & 31;
        bool has3 = (oq + 64) < ODIM;   // oq < 10
        float a0[4], a1[4], a2[4];
        float b0 = bp2[oq], b1v = bp2[oq+32], b2v = has3 ? bp2[oq+64] : 0.f;
        #pragma unroll
        for (int ni = 0; ni < 4; ++ni) { a0[ni] = b0; a1[ni] = b1v; a2[ni] = b2v; }
        for (int j = 0; j < MLPH; j += 4) {
            float4 hv[4];
            #pragma unroll
            for (int ni = 0; ni < 4; ++ni) hv[ni] = *(const float4*)&hid[nq*4+ni][j];
            #pragma unroll
            for (int jj = 0; jj < 4; ++jj) {
                float w0 = Wp2[(j+jj)*ODIM + oq];
                float w1 = Wp2[(j+jj)*ODIM + oq + 32];
                float w2 = has3 ? Wp2[(j+jj)*ODIM + oq + 64] : 0.f;
                float h0 = f4get(hv[0], jj), h1 = f4get(hv[1], jj);
                float h2 = f4get(hv[2], jj), h3 = f4get(hv[3], jj);
                a0[0] += h0*w0; a1[0] += h0*w1; a2[0] += h0*w2;
                a0[1] += h1*w0; a1[1] += h1*w1; a2[1] += h1*w2;
                a0[2] += h2*w0; a1[2] += h2*w1; a2[2] += h2*w2;
                a0[3] += h3*w0; a1[3] += h3*w1; a2[3] += h3*w2;
            }
        }
        #pragma unroll
        for (int ni = 0; ni < 4; ++ni) {
            size_t rowo = (size_t)(nb + nq*4 + ni) * ODIM;
            out[rowo + oq]      = a0[ni];
            out[rowo + oq + 32] = a1[ni];
            if (has3) out[rowo + oq + 64] = a2[ni];
        }
    }
}

// ---------------- launch ----------------

extern "C" void kernel_launch(void* const* d_in, const int* in_sizes, int n_in,
                              void* d_out, int out_size, void* d_ws, size_t ws_size,
                              hipStream_t stream) {
    const float* x    = (const float*)d_in[0];
    const int*   ei   = (const int*)  d_in[1];
    const float* W1   = (const float*)d_in[2];
    const float* a1s  = (const float*)d_in[3];
    const float* a1d  = (const float*)d_in[4];
    const float* b1   = (const float*)d_in[5];
    const float* W2   = (const float*)d_in[6];
    const float* a2s  = (const float*)d_in[7];
    const float* a2d  = (const float*)d_in[8];
    const float* b2   = (const float*)d_in[9];
    const float* Wp1  = (const float*)d_in[10];
    const float* bp1  = (const float*)d_in[11];
    const float* Wp2  = (const float*)d_in[12];
    const float* bp2  = (const float*)d_in[13];
    float* out = (float*)d_out;

    const int* esrc = ei;
    const int* edst = ei + EE;

    float* ws   = (float*)d_ws;
    float* bufA = ws;                      // h (N*64); first 12.8MB overlaid by tmp during CSR build
    float* bufB = bufA + NN*HID;           // layer outputs (N*64)
    float* hs   = bufB + NN*HID;           // N
    float* hd   = hs + NN;                 // N
    int* rowbeg = (int*)(hd + NN);         // N
    int* rowend = rowbeg + NN;             // N
    int* col    = rowend + NN;             // ET
    int* M      = col + ET;                // GA*NB
    int* colExcl= M + GA*NB;               // GA*NB
    int* colsum = colExcl + GA*NB;         // NB
    int* bucketBase = colsum + NB;         // NB+1
    unsigned long long* tmp = (unsigned long long*)bufA;   // EE packed records (12.8MB)

    // ---- CSR build (no global atomics; shared by both layers) ----
    k_partA_hist<<<GA, 256, 0, stream>>>(edst, M);
    k_scan_col  <<<NB, 256, 0, stream>>>(M, colExcl, colsum);
    k_scan_bkt  <<<1, 256, 0, stream>>>(colsum, bucketBase);
    k_partA_scat<<<GA, 256, 0, stream>>>(esrc, edst, colExcl, bucketBase, tmp);
    k_partB     <<<NB, 512, 0, stream>>>(tmp, bucketBase, rowbeg, rowend, col);

    // ---- GAT layer 1 (k_lin1 writes bufA after tmp is consumed; stream-ordered) ----
    k_lin1<<<NN/4, 256, 0, stream>>>(x, W1, a1s, a1d, bufA, hs, hd);
    k_gat <<<NN/4, 256, 0, stream>>>(rowbeg, rowend, col, hs, hd, bufA, b1, bufB);

    // ---- GAT layer 2 ----
    k_lin64<<<NN/32, 128, 0, stream>>>(bufB, W2, a2s, a2d, bufA, hs, hd);
    k_gat  <<<NN/4, 256, 0, stream>>>(rowbeg, rowend, col, hs, hd, bufA, b2, bufB);

    // ---- MLP head ----
    k_mlp<<<NN/32, 256, 0, stream>>>(bufB, Wp1, bp1, Wp2, bp2, out);
}

// Round 9
// 415.345 us; speedup vs baseline: 5.3518x; 5.3518x over previous
//
#include <hip/hip_runtime.h>
#include <math.h>

#define NN   100000
#define EE   1600000
#define ET   (EE + NN)          // edges + self-loops = 1,700,000
#define HID  64
#define MLPH 128
#define ODIM 74
#define SLOPE 0.2f

#define NB   196                // coarse buckets of 512 nodes (dst >> 9)
#define GA   800                // pass-A blocks
#define EPB  (EE / GA)          // 2000 edges per pass-A block

__device__ __forceinline__ float f4get(const float4& v, int i) {
    return i == 0 ? v.x : i == 1 ? v.y : i == 2 ? v.z : v.w;  // unrolled -> constant
}

// ================= CSR build: bucketed counting sort, no global atomics =================

// Pass A1: per-block LDS histogram over 196 coarse buckets
__global__ void k_partA_hist(const int* __restrict__ edst, int* __restrict__ M) {
    __shared__ int hist[NB];
    int t = threadIdx.x;
    if (t < NB) hist[t] = 0;
    __syncthreads();
    int base = blockIdx.x * EPB;
    for (int i = t; i < EPB; i += 256)
        atomicAdd(&hist[edst[base + i] >> 9], 1);
    __syncthreads();
    if (t < NB) M[blockIdx.x * NB + t] = hist[t];
}

// scan each bucket-column over the GA blocks: colExcl[b,k] = sum_{b'<b} M[b',k]; colsum[k]=total
__global__ void k_scan_col(const int* __restrict__ M, int* __restrict__ colExcl,
                           int* __restrict__ colsum) {
    __shared__ int sd[256];
    __shared__ int carry;
    int k = blockIdx.x, t = threadIdx.x;
    if (t == 0) carry = 0;
    __syncthreads();
    for (int c = 0; c < GA; c += 256) {
        int v = (c + t < GA) ? M[(c + t) * NB + k] : 0;
        sd[t] = v;
        __syncthreads();
        for (int o = 1; o < 256; o <<= 1) {
            int u = (t >= o) ? sd[t - o] : 0;
            __syncthreads();
            sd[t] += u;
            __syncthreads();
        }
        if (c + t < GA) colExcl[(c + t) * NB + k] = carry + sd[t] - v;
        __syncthreads();
        if (t == 255) carry += sd[255];
        __syncthreads();
    }
    if (t == 0) colsum[k] = carry;
}

// exclusive scan of the 196 bucket totals
__global__ void k_scan_bkt(const int* __restrict__ colsum, int* __restrict__ bucketBase) {
    __shared__ int sd[256];
    int t = threadIdx.x;
    int v = (t < NB) ? colsum[t] : 0;
    sd[t] = v;
    __syncthreads();
    for (int o = 1; o < 256; o <<= 1) {
        int u = (t >= o) ? sd[t - o] : 0;
        __syncthreads();
        sd[t] += u;
        __syncthreads();
    }
    if (t < NB) bucketBase[t] = sd[t] - v;
    if (t == NB - 1) bucketBase[NB] = sd[t];
}

// Pass A2: scatter packed (dst,src) into bucket-partitioned tmp via LDS cursors
__global__ void k_partA_scat(const int* __restrict__ esrc, const int* __restrict__ edst,
                             const int* __restrict__ colExcl, const int* __restrict__ bucketBase,
                             unsigned long long* __restrict__ tmp) {
    __shared__ int cur[NB];
    int t = threadIdx.x;
    if (t < NB) cur[t] = bucketBase[t] + colExcl[blockIdx.x * NB + t];
    __syncthreads();
    int base = blockIdx.x * EPB;
    for (int i = t; i < EPB; i += 256) {
        int s = esrc[base + i], d = edst[base + i];
        int pos = atomicAdd(&cur[d >> 9], 1);
        tmp[pos] = ((unsigned long long)(unsigned)d << 32) | (unsigned)s;
    }
}

// Pass B: one block per bucket — LDS deg hist + LDS scan + LDS-cursor scatter into col;
// emits rowbeg/rowend with self-loop pre-placed at each row head.
__global__ __launch_bounds__(512) void k_partB(
        const unsigned long long* __restrict__ tmp, const int* __restrict__ bucketBase,
        int* __restrict__ rowbeg, int* __restrict__ rowend, int* __restrict__ col) {
    __shared__ int deg[512];
    __shared__ int rb[512];
    __shared__ int cur[512];
    int k = blockIdx.x, t = threadIdx.x;
    int lo = bucketBase[k], hi = bucketBase[k + 1];
    int nodeBase = k << 9;
    int nNodes = (NN - nodeBase < 512) ? (NN - nodeBase) : 512;

    deg[t] = 0;
    __syncthreads();
    for (int i = lo + t; i < hi; i += 512)
        atomicAdd(&deg[(int)(tmp[i] >> 32) - nodeBase], 1);
    __syncthreads();

    // exclusive scan over (deg + 1 self-loop) for the bucket's nodes
    int v = (t < nNodes) ? deg[t] + 1 : 0;
    rb[t] = v;
    __syncthreads();
    for (int o = 1; o < 512; o <<= 1) {
        int u = (t >= o) ? rb[t - o] : 0;
        __syncthreads();
        rb[t] += u;
        __syncthreads();
    }
    // global col segment for bucket k starts at bucketBase[k] + (#self-loops before) = nodeBase
    int myBeg = lo + nodeBase + rb[t] - v;
    if (t < nNodes) {
        int g = nodeBase + t;
        rowbeg[g] = myBeg;
        rowend[g] = myBeg + deg[t] + 1;
        col[myBeg] = g;              // self-loop first in row
        cur[t] = myBeg + 1;
    }
    __syncthreads();
    for (int i = lo + t; i < hi; i += 512) {
        unsigned long long e = tmp[i];
        int dLow = (int)(e >> 32) - nodeBase;
        int pos = atomicAdd(&cur[dLow], 1);
        col[pos] = (int)(e & 0xffffffffu);
    }
}

// ---------------- dense prologues ----------------

// h = x @ W1 (IN_DIM=3) + hs/hd wave reductions
__global__ void k_lin1(const float* __restrict__ x, const float* __restrict__ W,
                       const float* __restrict__ asrc, const float* __restrict__ adst,
                       float* __restrict__ h, float* __restrict__ hs, float* __restrict__ hd) {
    int node = blockIdx.x * 4 + (threadIdx.x >> 6);
    int f    = threadIdx.x & 63;
    float x0 = x[node*3+0], x1 = x[node*3+1], x2 = x[node*3+2];
    float v  = x0*W[f] + x1*W[64+f] + x2*W[128+f];
    h[node*64+f] = v;
    float ps = v*asrc[f], pd = v*adst[f];
    #pragma unroll
    for (int o = 32; o > 0; o >>= 1) { ps += __shfl_down(ps, o); pd += __shfl_down(pd, o); }
    if (f == 0) { hs[node] = ps; hd[node] = pd; }
}

// h = xin @ W (64x64): 32 nodes/block, 128 threads, 4x4 tile/thread, LDS-staged W
__global__ __launch_bounds__(128) void k_lin64(
        const float* __restrict__ xin, const float* __restrict__ W,
        const float* __restrict__ asrc, const float* __restrict__ adst,
        float* __restrict__ h, float* __restrict__ hs, float* __restrict__ hd) {
    __shared__ __align__(16) float xr[32][64];     // 8 KB (x rows, later reused for h rows)
    __shared__ __align__(16) float wl[64*64];      // 16 KB, [k][o] layout
    int t  = threadIdx.x;
    int nb = blockIdx.x * 32;
    for (int i = t; i < 32*64; i += 128) xr[i >> 6][i & 63] = xin[nb*64 + i];
    for (int i = t; i < 64*64;  i += 128) wl[i] = W[i];
    __syncthreads();

    int nq = t >> 4;    // 0..7 (4 nodes each)
    int hq = t & 15;    // 0..15 (4 outs each)
    float acc[4][4] = {};
    #pragma unroll 4
    for (int k = 0; k < 64; k += 4) {
        float4 xv[4];
        #pragma unroll
        for (int ni = 0; ni < 4; ++ni) xv[ni] = *(const float4*)&xr[nq*4+ni][k];
        #pragma unroll
        for (int kk = 0; kk < 4; ++kk) {
            float4 wv = *(const float4*)&wl[(k+kk)*64 + hq*4];
            #pragma unroll
            for (int ni = 0; ni < 4; ++ni) {
                float xs = f4get(xv[ni], kk);
                acc[ni][0] += xs*wv.x; acc[ni][1] += xs*wv.y;
                acc[ni][2] += xs*wv.z; acc[ni][3] += xs*wv.w;
            }
        }
    }
    float4 res[4];
    #pragma unroll
    for (int ni = 0; ni < 4; ++ni) {
        res[ni] = make_float4(acc[ni][0], acc[ni][1], acc[ni][2], acc[ni][3]);
        *(float4*)&h[(size_t)(nb + nq*4 + ni)*64 + hq*4] = res[ni];
    }
    __syncthreads();                 // all xr reads done
    #pragma unroll
    for (int ni = 0; ni < 4; ++ni) *(float4*)&xr[nq*4+ni][hq*4] = res[ni];
    __syncthreads();

    // hs/hd: 2 waves x 16 nodes, lane = feature
    int wv_  = t >> 6;
    int lane = t & 63;
    for (int ni = 0; ni < 16; ++ni) {
        int node = wv_*16 + ni;
        float v  = xr[node][lane];
        float ps = v*asrc[lane], pd = v*adst[lane];
        #pragma unroll
        for (int o = 32; o > 0; o >>= 1) { ps += __shfl_down(ps, o); pd += __shfl_down(pd, o); }
        if (lane == 0) { hs[nb+node] = ps; hd[nb+node] = pd; }
    }
}

// ---------------- fused GAT aggregate: one wave per dst node ----------------
__global__ void k_gat(const int* __restrict__ rowbeg, const int* __restrict__ rowend,
                      const int* __restrict__ col,
                      const float* __restrict__ hs, const float* __restrict__ hd,
                      const float* __restrict__ h, const float* __restrict__ bias,
                      float* __restrict__ out) {
    __shared__ float se[4][128];
    __shared__ int   sc[4][128];
    int w    = threadIdx.x >> 6;
    int lane = threadIdx.x & 63;
    int n    = blockIdx.x * 4 + w;
    float* e_ = se[w];
    int*   c_ = sc[w];

    int base = rowbeg[n];
    int d    = rowend[n] - base;          // >=1 (self-loop)
    float hdn = hd[n];

    // phase A1: scores (+ stash col) + wave max
    float mymax = -INFINITY;
    for (int k = lane; k < d; k += 64) {
        int s = col[base + k];
        float scv = hs[s] + hdn;
        scv = (scv > 0.f) ? scv : SLOPE * scv;
        if (k < 128) { e_[k] = scv; c_[k] = s; }
        mymax = fmaxf(mymax, scv);
    }
    #pragma unroll
    for (int o = 32; o > 0; o >>= 1) mymax = fmaxf(mymax, __shfl_xor(mymax, o));

    // phase A2: exp + wave sum (own elements only)
    float mysum = 0.f;
    for (int k = lane; k < d; k += 64) {
        float scv;
        if (k < 128) scv = e_[k];
        else {
            int s = col[base + k];
            scv = hs[s] + hdn;
            scv = (scv > 0.f) ? scv : SLOPE * scv;
        }
        float p = expf(scv - mymax);
        if (k < 128) e_[k] = p;
        mysum += p;
    }
    #pragma unroll
    for (int o = 32; o > 0; o >>= 1) mysum += __shfl_xor(mysum, o);
    float inv = 1.f / mysum;

    __syncthreads();   // publish p/col for cross-lane reads

    // phase B: unroll x4, 4 independent h-row loads in flight
    int dl = (d < 128) ? d : 128;
    float accf = 0.f;
    int k = 0;
    for (; k + 4 <= dl; k += 4) {
        int s0 = c_[k], s1 = c_[k+1], s2 = c_[k+2], s3 = c_[k+3];
        float p0 = e_[k], p1 = e_[k+1], p2 = e_[k+2], p3 = e_[k+3];
        float h0 = h[(size_t)s0*64 + lane];
        float h1 = h[(size_t)s1*64 + lane];
        float h2 = h[(size_t)s2*64 + lane];
        float h3 = h[(size_t)s3*64 + lane];
        accf += p0*h0 + p1*h1 + p2*h2 + p3*h3;
    }
    for (; k < dl; ++k) accf += e_[k] * h[(size_t)c_[k]*64 + lane];
    for (; k < d; ++k) {                   // d>128 spill path (never hit at E[deg]=17)
        int s = col[base + k];
        float scv = hs[s] + hdn;
        scv = (scv > 0.f) ? scv : SLOPE * scv;
        accf += expf(scv - mymax) * h[(size_t)s*64 + lane];
    }
    out[n*64 + lane] = fmaxf(accf*inv + bias[lane], 0.f);
}

// ---------------- MLP head v5: float4 LDS reads, BOUNDED unroll (no spill) ----------------
// v4 lesson: without an unroll cap the compiler fully unrolls (trip counts 16/32 are
// compile-time) and hoists all global weight loads -> 256 VGPR -> 3.7GB scratch traffic.
__global__ __launch_bounds__(256) void k_mlp(
        const float* __restrict__ xin,
        const float* __restrict__ Wp1, const float* __restrict__ bp1,
        const float* __restrict__ Wp2, const float* __restrict__ bp2,
        float* __restrict__ out) {
    __shared__ __align__(16) float xr[32][64];     // 8 KB
    __shared__ __align__(16) float hid[32][132];   // 16.9 KB; row stride 132 = 33x16B (f4-aligned)
    int t  = threadIdx.x;
    int nb = blockIdx.x * 32;
    int nq = t >> 5;      // 0..7  (4 nodes each)
    int hq = t & 31;      // 0..31 (4 hidden units each in phase 1)

    for (int i = t; i < 32*64; i += 256) xr[i >> 6][i & 63] = xin[(size_t)nb*64 + i];
    __syncthreads();

    // phase 1: hid = relu(x @ Wp1 + bp1); x rows via ds_read_b128, weights from global (L1)
    {
        float4 bv = *(const float4*)&bp1[hq*4];
        float acc[4][4];
        #pragma unroll
        for (int ni = 0; ni < 4; ++ni) {
            acc[ni][0] = bv.x; acc[ni][1] = bv.y; acc[ni][2] = bv.z; acc[ni][3] = bv.w;
        }
        #pragma unroll 2
        for (int k = 0; k < 64; k += 4) {
            float4 xv[4];
            #pragma unroll
            for (int ni = 0; ni < 4; ++ni) xv[ni] = *(const float4*)&xr[nq*4+ni][k];
            #pragma unroll
            for (int kk = 0; kk < 4; ++kk) {
                float4 wv = *(const float4*)&Wp1[(k+kk)*MLPH + hq*4];
                #pragma unroll
                for (int ni = 0; ni < 4; ++ni) {
                    float xs = f4get(xv[ni], kk);
                    acc[ni][0] += xs*wv.x; acc[ni][1] += xs*wv.y;
                    acc[ni][2] += xs*wv.z; acc[ni][3] += xs*wv.w;
                }
            }
        }
        #pragma unroll
        for (int ni = 0; ni < 4; ++ni)
            *(float4*)&hid[nq*4+ni][hq*4] = make_float4(
                fmaxf(acc[ni][0], 0.f), fmaxf(acc[ni][1], 0.f),
                fmaxf(acc[ni][2], 0.f), fmaxf(acc[ni][3], 0.f));
    }
    __syncthreads();

    // phase 2: out = hid @ Wp2 + bp2; hid rows via ds_read_b128;
    // thread = (nq: 4 nodes, oq: outs oq, oq+32, oq+64)
    {
        int oq = t & 31;
        bool has3 = (oq + 64) < ODIM;   // oq < 10
        float a0[4], a1[4], a2[4];
        float b0 = bp2[oq], b1v = bp2[oq+32], b2v = has3 ? bp2[oq+64] : 0.f;
        #pragma unroll
        for (int ni = 0; ni < 4; ++ni) { a0[ni] = b0; a1[ni] = b1v; a2[ni] = b2v; }
        #pragma unroll 2
        for (int j = 0; j < MLPH; j += 4) {
            float4 hv[4];
            #pragma unroll
            for (int ni = 0; ni < 4; ++ni) hv[ni] = *(const float4*)&hid[nq*4+ni][j];
            #pragma unroll
            for (int jj = 0; jj < 4; ++jj) {
                float w0 = Wp2[(j+jj)*ODIM + oq];
                float w1 = Wp2[(j+jj)*ODIM + oq + 32];
                float w2 = has3 ? Wp2[(j+jj)*ODIM + oq + 64] : 0.f;
                float h0 = f4get(hv[0], jj), h1 = f4get(hv[1], jj);
                float h2 = f4get(hv[2], jj), h3 = f4get(hv[3], jj);
                a0[0] += h0*w0; a1[0] += h0*w1; a2[0] += h0*w2;
                a0[1] += h1*w0; a1[1] += h1*w1; a2[1] += h1*w2;
                a0[2] += h2*w0; a1[2] += h2*w1; a2[2] += h2*w2;
                a0[3] += h3*w0; a1[3] += h3*w1; a2[3] += h3*w2;
            }
        }
        #pragma unroll
        for (int ni = 0; ni < 4; ++ni) {
            size_t rowo = (size_t)(nb + nq*4 + ni) * ODIM;
            out[rowo + oq]      = a0[ni];
            out[rowo + oq + 32] = a1[ni];
            if (has3) out[rowo + oq + 64] = a2[ni];
        }
    }
}

// ---------------- launch ----------------

extern "C" void kernel_launch(void* const* d_in, const int* in_sizes, int n_in,
                              void* d_out, int out_size, void* d_ws, size_t ws_size,
                              hipStream_t stream) {
    const float* x    = (const float*)d_in[0];
    const int*   ei   = (const int*)  d_in[1];
    const float* W1   = (const float*)d_in[2];
    const float* a1s  = (const float*)d_in[3];
    const float* a1d  = (const float*)d_in[4];
    const float* b1   = (const float*)d_in[5];
    const float* W2   = (const float*)d_in[6];
    const float* a2s  = (const float*)d_in[7];
    const float* a2d  = (const float*)d_in[8];
    const float* b2   = (const float*)d_in[9];
    const float* Wp1  = (const float*)d_in[10];
    const float* bp1  = (const float*)d_in[11];
    const float* Wp2  = (const float*)d_in[12];
    const float* bp2  = (const float*)d_in[13];
    float* out = (float*)d_out;

    const int* esrc = ei;
    const int* edst = ei + EE;

    float* ws   = (float*)d_ws;
    float* bufA = ws;                      // h (N*64); first 12.8MB overlaid by tmp during CSR build
    float* bufB = bufA + NN*HID;           // layer outputs (N*64)
    float* hs   = bufB + NN*HID;           // N
    float* hd   = hs + NN;                 // N
    int* rowbeg = (int*)(hd + NN);         // N
    int* rowend = rowbeg + NN;             // N
    int* col    = rowend + NN;             // ET
    int* M      = col + ET;                // GA*NB
    int* colExcl= M + GA*NB;               // GA*NB
    int* colsum = colExcl + GA*NB;         // NB
    int* bucketBase = colsum + NB;         // NB+1
    unsigned long long* tmp = (unsigned long long*)bufA;   // EE packed records (12.8MB)

    // ---- CSR build (no global atomics; shared by both layers) ----
    k_partA_hist<<<GA, 256, 0, stream>>>(edst, M);
    k_scan_col  <<<NB, 256, 0, stream>>>(M, colExcl, colsum);
    k_scan_bkt  <<<1, 256, 0, stream>>>(colsum, bucketBase);
    k_partA_scat<<<GA, 256, 0, stream>>>(esrc, edst, colExcl, bucketBase, tmp);
    k_partB     <<<NB, 512, 0, stream>>>(tmp, bucketBase, rowbeg, rowend, col);

    // ---- GAT layer 1 (k_lin1 writes bufA after tmp is consumed; stream-ordered) ----
    k_lin1<<<NN/4, 256, 0, stream>>>(x, W1, a1s, a1d, bufA, hs, hd);
    k_gat <<<NN/4, 256, 0, stream>>>(rowbeg, rowend, col, hs, hd, bufA, b1, bufB);

    // ---- GAT layer 2 ----
    k_lin64<<<NN/32, 128, 0, stream>>>(bufB, W2, a2s, a2d, bufA, hs, hd);
    k_gat  <<<NN/4, 256, 0, stream>>>(rowbeg, rowend, col, hs, hd, bufA, b2, bufB);

    // ---- MLP head ----
    k_mlp<<<NN/32, 256, 0, stream>>>(bufB, Wp1, bp1, Wp2, bp2, out);
}